// Round 2
// baseline (460.140 us; speedup 1.0000x reference)
//
#include <hip/hip_runtime.h>
#include <math.h>

#define NH_ 8
#define L_ 3
#define P_ 8
#define HD_ 32
#define C_ 256
#define B_ 4
#define NQ 2048
#define S_ 13125

// level geometry (fixed by setup_inputs; inputs are restored to pristine each run)
// LW/LH/LSTART indexed only by compile-time constants after full unroll.
__device__ __constant__ const int kLW[3]     = {100, 50, 25};
__device__ __constant__ const int kLH[3]     = {100, 50, 25};
__device__ __constant__ const int kLSTART[3] = {0, 10000, 12500};

// ---------------------------------------------------------------------------
// Generic fp32 64x64-tile GEMM, K=256 fixed, 256 threads, 4x4 microtile.
// MODE 0: A=memory[b] (blockIdx.z=b), W1=W_val -> value [B][NH][S][HD] (+b_val)
// MODE 1: A=query (8192x256), W1=W_off (ldb 384), W2=W_attn (ldb 192)
//         -> O1 = off buffer [8192][384], O2 = attn logits [8192][192]
// MODE 2: A=out_pre (8192x256), W1=W_out -> O1 = d_out [8192][256] (+b_out)
// ---------------------------------------------------------------------------
template <int MODE>
__global__ __launch_bounds__(256) void gemm64(
    const float* __restrict__ A,
    const float* __restrict__ W1, const float* __restrict__ W2,
    const float* __restrict__ bias1, const float* __restrict__ bias2,
    float* __restrict__ O1, float* __restrict__ O2)
{
    const int tid = threadIdx.x;
    const int rb = blockIdx.x, cb = blockIdx.y, zb = blockIdx.z;

    int M;
    const float* Asrc;
    if constexpr (MODE == 0) { M = S_;     Asrc = A + (size_t)zb * S_ * C_; }
    else                     { M = B_*NQ;  Asrc = A; }

    const int row0 = rb * 64, col0 = cb * 64;

    // select B matrix / leading dim for this column block
    const float* Bw; int ldb; int n0;
    if constexpr (MODE == 1) {
        if (col0 < 384) { Bw = W1; ldb = 384; n0 = col0; }
        else            { Bw = W2; ldb = 192; n0 = col0 - 384; }
    } else { Bw = W1; ldb = 256; n0 = col0; }

    __shared__ float As[16][68];  // [k][row], padded: 68*4=272B stride (16B-aligned)
    __shared__ float Bs[16][64];  // [k][col]

    const int tx = tid & 15, ty = tid >> 4;
    const int lr = tid >> 2, lk = (tid & 3) * 4;   // A tile load: row lr, k-offset lk
    const int bk = tid >> 4, bc = (tid & 15) * 4;  // B tile load

    float acc[4][4] = {};

    for (int k0 = 0; k0 < 256; k0 += 16) {
        float4 av;
        const int gr = row0 + lr;
        if (gr < M) av = *(const float4*)(Asrc + (size_t)gr * 256 + k0 + lk);
        else        av = float4{0.f, 0.f, 0.f, 0.f};
        const float4 bv = *(const float4*)(Bw + (size_t)(k0 + bk) * ldb + n0 + bc);

        As[lk + 0][lr] = av.x; As[lk + 1][lr] = av.y;
        As[lk + 2][lr] = av.z; As[lk + 3][lr] = av.w;
        *(float4*)&Bs[bk][bc] = bv;
        __syncthreads();

        #pragma unroll
        for (int kk = 0; kk < 16; ++kk) {
            float a[4], b[4];
            #pragma unroll
            for (int i = 0; i < 4; ++i) a[i] = As[kk][ty * 4 + i];
            #pragma unroll
            for (int j = 0; j < 4; ++j) b[j] = Bs[kk][tx * 4 + j];
            #pragma unroll
            for (int i = 0; i < 4; ++i)
                #pragma unroll
                for (int j = 0; j < 4; ++j)
                    acc[i][j] = fmaf(a[i], b[j], acc[i][j]);
        }
        __syncthreads();
    }

    #pragma unroll
    for (int i = 0; i < 4; ++i) {
        const int gr = row0 + ty * 4 + i;
        if (gr >= M) continue;
        #pragma unroll
        for (int j = 0; j < 4; ++j) {
            const int n = col0 + tx * 4 + j;
            const float v = acc[i][j];
            if constexpr (MODE == 0) {
                const int h = n >> 5, d = n & 31;
                O1[(((size_t)zb * NH_ + h) * S_ + gr) * HD_ + d] = v + bias1[n];
            } else if constexpr (MODE == 1) {
                if (n < 384) O1[(size_t)gr * 384 + n]         = v + bias1[n];
                else         O2[(size_t)gr * 192 + (n - 384)] = v + bias2[n - 384];
            } else {
                O1[(size_t)gr * 256 + n] = v + bias1[n];
            }
        }
    }
}

// ---------------------------------------------------------------------------
// Sampling kernel: one wave per (b,h,q). Half-wave (32 lanes, d=lane&31)
// handles one (l,p) sample per iteration; 12 iterations cover L*P=24.
// Softmax over the 24 logits done in-register (fully unrolled, static idx).
// Grid decode groups q-consecutive waves under the same (b,h) for L2 reuse.
// ---------------------------------------------------------------------------
__global__ __launch_bounds__(256) void sample_kernel(
    const float* __restrict__ value,   // [B][NH][S][HD]
    const float* __restrict__ offs,    // [8192][384]
    const float* __restrict__ logits,  // [8192][192]
    const float* __restrict__ refp,    // [B][NQ][2]
    float* __restrict__ out_pre)       // [8192][256] = [b][q][h*32+d]
{
    const int wib = threadIdx.x >> 6;            // wave in block (0..3)
    const int lane = threadIdx.x & 63;
    const int half = lane >> 5, dl = lane & 31;

    const int bh = blockIdx.x >> 9;              // 512 blocks per (b,h)
    const int q  = ((blockIdx.x & 511) << 2) + wib;
    const int b  = bh >> 3, h = bh & 7;
    const int row = b * NQ + q;

    // softmax over 24 logits for this (b,q,h)
    const float* lg = logits + (size_t)row * 192 + h * 24;
    float l[24];
    float m = -INFINITY;
    #pragma unroll
    for (int j = 0; j < 24; ++j) { l[j] = lg[j]; m = fmaxf(m, l[j]); }
    float s = 0.f;
    #pragma unroll
    for (int j = 0; j < 24; ++j) { l[j] = __expf(l[j] - m); s += l[j]; }
    const float inv = 1.0f / s;

    const float refx = refp[(size_t)row * 2 + 0];
    const float refy = refp[(size_t)row * 2 + 1];
    const float* off = offs + (size_t)row * 384 + h * 48;  // h*L*P*2

    float acc = 0.f;
    #pragma unroll
    for (int it = 0; it < 12; ++it) {
        const int lvl = it >> 2;                 // compile-time after unroll
        const int w  = kLW[lvl], hh = kLH[lvl], st = kLSTART[lvl];

        // per-lane sample index j = it*2 + half (same level for both halves)
        const float ox = off[(it * 2 + half) * 2 + 0];
        const float oy = off[(it * 2 + half) * 2 + 1];

        // x = loc_x*w - 0.5 where loc_x = refx + ox/w  =>  x = refx*w + ox - 0.5
        const float x = refx * (float)w  + ox - 0.5f;
        const float y = refy * (float)hh + oy - 0.5f;
        const float x0 = floorf(x), y0 = floorf(y);
        const float fx = x - x0, fy = y - y0;
        const int ix = (int)x0, iy = (int)y0;

        const bool vx0 = (ix >= 0) & (ix < w);
        const bool vx1 = (ix + 1 >= 0) & (ix + 1 < w);
        const bool vy0 = (iy >= 0) & (iy < hh);
        const bool vy1 = (iy + 1 >= 0) & (iy + 1 < hh);
        const int xc0 = min(max(ix, 0), w - 1),  xc1 = min(max(ix + 1, 0), w - 1);
        const int yc0 = min(max(iy, 0), hh - 1), yc1 = min(max(iy + 1, 0), hh - 1);

        const float* vb = value + (((size_t)b * NH_ + h) * S_ + st) * HD_;
        const float v00 = (vx0 && vy0) ? vb[(size_t)(yc0 * w + xc0) * HD_ + dl] : 0.f;
        const float v10 = (vx1 && vy0) ? vb[(size_t)(yc0 * w + xc1) * HD_ + dl] : 0.f;
        const float v01 = (vx0 && vy1) ? vb[(size_t)(yc1 * w + xc0) * HD_ + dl] : 0.f;
        const float v11 = (vx1 && vy1) ? vb[(size_t)(yc1 * w + xc1) * HD_ + dl] : 0.f;

        const float w00 = (1.f - fx) * (1.f - fy), w10 = fx * (1.f - fy);
        const float w01 = (1.f - fx) * fy,         w11 = fx * fy;
        const float sv = v00 * w00 + v10 * w10 + v01 * w01 + v11 * w11;

        const float aw = (half ? l[it * 2 + 1] : l[it * 2]) * inv;
        acc = fmaf(aw, sv, acc);
    }

    // combine the two halves (even/odd samples) and store once
    acc += __shfl_xor(acc, 32, 64);
    if (half == 0)
        out_pre[(size_t)row * 256 + h * HD_ + dl] = acc;
}

extern "C" void kernel_launch(void* const* d_in, const int* in_sizes, int n_in,
                              void* d_out, int out_size, void* d_ws, size_t ws_size,
                              hipStream_t stream)
{
    const float* query  = (const float*)d_in[0];
    const float* memory = (const float*)d_in[1];
    const float* refp   = (const float*)d_in[2];
    const float* W_off  = (const float*)d_in[3];
    const float* b_off  = (const float*)d_in[4];
    const float* W_attn = (const float*)d_in[5];
    const float* b_attn = (const float*)d_in[6];
    const float* W_val  = (const float*)d_in[7];
    const float* b_val  = (const float*)d_in[8];
    const float* W_out  = (const float*)d_in[9];
    const float* b_out  = (const float*)d_in[10];

    float* ws      = (float*)d_ws;
    float* value   = ws;                                    // 13,440,000 f32
    float* offb    = value + (size_t)B_ * NH_ * S_ * HD_;   // + 3,145,728
    float* attnb   = offb  + (size_t)B_ * NQ * 384;         // + 1,572,864
    float* out_pre = attnb + (size_t)B_ * NQ * 192;         // + 2,097,152
    float* out     = (float*)d_out;                         // total ~81 MB ws

    // 1) value = memory @ W_val + b_val  -> [B][NH][S][HD]
    hipLaunchKernelGGL((gemm64<0>), dim3((S_ + 63) / 64, 4, B_), dim3(256), 0, stream,
                       memory, W_val, nullptr, b_val, nullptr, value, nullptr);
    // 2) off/attn logits = query @ [W_off | W_attn]
    hipLaunchKernelGGL((gemm64<1>), dim3(128, 9, 1), dim3(256), 0, stream,
                       query, W_off, W_attn, b_off, b_attn, offb, attnb);
    // 3) softmax + bilinear sampling + head-dim accumulate
    hipLaunchKernelGGL(sample_kernel, dim3(16384), dim3(256), 0, stream,
                       value, offb, attnb, refp, out_pre);
    // 4) out = out_pre @ W_out + b_out
    hipLaunchKernelGGL((gemm64<2>), dim3(128, 4, 1), dim3(256), 0, stream,
                       out_pre, W_out, nullptr, b_out, nullptr, out, nullptr);
}

// Round 4
// 246.553 us; speedup vs baseline: 1.8663x; 1.8663x over previous
//
#include <hip/hip_runtime.h>
#include <math.h>

#define NH_ 8
#define L_ 3
#define P_ 8
#define HD_ 32
#define C_ 256
#define B_ 4
#define NQ 2048
#define S_ 13125

typedef unsigned short ushort;
typedef unsigned int uint;

__device__ __constant__ const int kLW[3]     = {100, 50, 25};
__device__ __constant__ const int kLH[3]     = {100, 50, 25};
__device__ __constant__ const int kLSTART[3] = {0, 10000, 12500};

using short8 = __attribute__((ext_vector_type(8))) short;
using f32x4  = __attribute__((ext_vector_type(4))) float;

typedef unsigned int u32_as1 __attribute__((address_space(1)));
typedef unsigned int u32_as3 __attribute__((address_space(3)));

__device__ __forceinline__ void gload16(const ushort* g, ushort* l) {
    // async global->LDS, 16B per lane, LDS dest = wave-uniform base + lane*16
    __builtin_amdgcn_global_load_lds((const u32_as1*)g, (u32_as3*)l, 16, 0, 0);
}

__device__ __forceinline__ ushort f2bf(float f) {
    union { float f; uint i; } v; v.f = f;
    const uint x = v.i;
    return (ushort)((x + 0x7FFFu + ((x >> 16) & 1u)) >> 16);  // RTNE
}
__device__ __forceinline__ float bf2f(ushort u) {
    union { uint i; float f; } v; v.i = ((uint)u) << 16; return v.f;
}
__device__ __forceinline__ uint pk2(float lo, float hi) {
    return (uint)f2bf(lo) | ((uint)f2bf(hi) << 16);
}

// ---------------------------------------------------------------------------
// Convert fp32 inputs to bf16 staging buffers; weights transposed to [N][K].
// Segments (threads): mem 1,680,000 (x8 elems) | query 262,144 (x8)
//                   | W_valT 65,536 | WcatT 147,456 | W_outT 65,536
// ---------------------------------------------------------------------------
__global__ __launch_bounds__(256) void convert_kernel(
    const float* __restrict__ memory, const float* __restrict__ query,
    const float* __restrict__ W_off, const float* __restrict__ W_attn,
    const float* __restrict__ W_val, const float* __restrict__ W_out,
    ushort* __restrict__ memB, ushort* __restrict__ queryB,
    ushort* __restrict__ WcatT, ushort* __restrict__ W_valT,
    ushort* __restrict__ W_outT)
{
    const uint id = blockIdx.x * 256u + threadIdx.x;
    if (id < 1680000u) {
        const float4 a = *(const float4*)(memory + (size_t)id * 8);
        const float4 b = *(const float4*)(memory + (size_t)id * 8 + 4);
        uint4 o; o.x = pk2(a.x, a.y); o.y = pk2(a.z, a.w);
                 o.z = pk2(b.x, b.y); o.w = pk2(b.z, b.w);
        *(uint4*)(memB + (size_t)id * 8) = o;
    } else if (id < 1942144u) {
        const uint i = id - 1680000u;
        const float4 a = *(const float4*)(query + (size_t)i * 8);
        const float4 b = *(const float4*)(query + (size_t)i * 8 + 4);
        uint4 o; o.x = pk2(a.x, a.y); o.y = pk2(a.z, a.w);
                 o.z = pk2(b.x, b.y); o.w = pk2(b.z, b.w);
        *(uint4*)(queryB + (size_t)i * 8) = o;
    } else if (id < 2007680u) {
        const uint i = id - 1942144u;           // W_valT[n][k] = W_val[k][n]
        const uint n = i >> 8, k = i & 255u;
        W_valT[i] = f2bf(W_val[k * 256 + n]);
    } else if (id < 2155136u) {
        const uint i = id - 2007680u;           // WcatT[n][k], n<384: W_off, else W_attn
        const uint n = i >> 8, k = i & 255u;
        WcatT[i] = f2bf(n < 384u ? W_off[k * 384 + n] : W_attn[k * 192 + (n - 384)]);
    } else if (id < 2220672u) {
        const uint i = id - 2155136u;
        const uint n = i >> 8, k = i & 255u;
        W_outT[i] = f2bf(W_out[k * 256 + n]);
    }
}

// ---------------------------------------------------------------------------
// bf16 MFMA GEMM: C[M][N] = A[M][256] * WT[N][256]^T, f32 accumulate.
// 128x128 tile, 4 waves (2x2, 64x64 each), K-step 32, 2-phase LDS dbuf via
// global_load_lds (chunk-major LDS layout: addr = kchunk*2048B + idx*16B,
// conflict-free ds_read_b128 frag reads).
// MODE 0: A=memB(batch z), WT=W_valT -> value bf16 [B][NH][S][HD] (+b_val)
// MODE 1: A=queryB,        WT=WcatT  -> projQ f32 [8192][576] (+b_off|b_attn)
// MODE 2: A=out_preB,      WT=W_outT -> d_out f32 [8192][256] (+b_out)
// ---------------------------------------------------------------------------
template <int MODE>
__global__ __launch_bounds__(256) void gemm_mfma(
    const ushort* __restrict__ A, const ushort* __restrict__ WT,
    const float* __restrict__ bias1, const float* __restrict__ bias2,
    void* __restrict__ outp)
{
    const int tid = threadIdx.x;
    const int wid = tid >> 6, lane = tid & 63;
    const int l15 = lane & 15, kcl = lane >> 4;
    const int wr = wid >> 1, wc = wid & 1;

    int M, N;
    const ushort* Ab;
    if constexpr (MODE == 0) { M = S_;  N = 256; Ab = A + (size_t)blockIdx.z * S_ * 256; }
    else if constexpr (MODE == 1) { M = 8192; N = 576; Ab = A; }
    else { M = 8192; N = 256; Ab = A; }

    const int row0 = blockIdx.x * 128, n0 = blockIdx.y * 128;

    __shared__ ushort As[2][4096];   // [kchunk(=wave)][128 rows][8 k] ushorts
    __shared__ ushort Bs[2][4096];

    f32x4 acc[4][4] = {};

    auto stage = [&](int buf, int k0) {
        #pragma unroll
        for (int rh = 0; rh < 2; ++rh) {
            int r = row0 + rh * 64 + lane;
            if (MODE == 0) r = min(r, M - 1);
            gload16(Ab + (size_t)r * 256 + k0 + wid * 8,
                    &As[buf][wid * 1024 + rh * 512]);
            int c = n0 + rh * 64 + lane;
            if (MODE == 1) c = min(c, N - 1);
            gload16(WT + (size_t)c * 256 + k0 + wid * 8,
                    &Bs[buf][wid * 1024 + rh * 512]);
        }
    };

    stage(0, 0);
    __syncthreads();   // compiler emits vmcnt(0) drain before s_barrier

    #pragma unroll
    for (int kt = 0; kt < 8; ++kt) {
        const int cur = kt & 1;
        if (kt < 7) stage(cur ^ 1, (kt + 1) * 32);

        short8 af[4], bf[4];
        #pragma unroll
        for (int mi = 0; mi < 4; ++mi)
            af[mi] = *(const short8*)&As[cur][kcl * 1024 + (wr * 64 + mi * 16 + l15) * 8];
        #pragma unroll
        for (int ni = 0; ni < 4; ++ni)
            bf[ni] = *(const short8*)&Bs[cur][kcl * 1024 + (wc * 64 + ni * 16 + l15) * 8];
        #pragma unroll
        for (int mi = 0; mi < 4; ++mi)
            #pragma unroll
            for (int ni = 0; ni < 4; ++ni)
                acc[mi][ni] = __builtin_amdgcn_mfma_f32_16x16x32_bf16(
                    af[mi], bf[ni], acc[mi][ni], 0, 0, 0);
        __syncthreads();
    }

    // epilogue: C/D layout col = lane&15, row = (lane>>4)*4 + reg
    #pragma unroll
    for (int ni = 0; ni < 4; ++ni) {
        const int n = n0 + wc * 64 + ni * 16 + l15;
        if constexpr (MODE == 0) {
            ushort* value = (ushort*)outp;
            const int h = n >> 5, d = n & 31;
            const float bv = bias1[n];
            #pragma unroll
            for (int mi = 0; mi < 4; ++mi)
                #pragma unroll
                for (int r = 0; r < 4; ++r) {
                    const int s = row0 + wr * 64 + mi * 16 + kcl * 4 + r;
                    if (s < S_)
                        value[(((size_t)blockIdx.z * NH_ + h) * S_ + s) * HD_ + d] =
                            f2bf(acc[mi][ni][r] + bv);
                }
        } else if constexpr (MODE == 1) {
            if (n < 576) {
                float* o = (float*)outp;
                const float bv = (n < 384) ? bias1[n] : bias2[n - 384];
                #pragma unroll
                for (int mi = 0; mi < 4; ++mi)
                    #pragma unroll
                    for (int r = 0; r < 4; ++r) {
                        const int gr = row0 + wr * 64 + mi * 16 + kcl * 4 + r;
                        o[(size_t)gr * 576 + n] = acc[mi][ni][r] + bv;
                    }
            }
        } else {
            float* o = (float*)outp;
            const float bv = bias1[n];
            #pragma unroll
            for (int mi = 0; mi < 4; ++mi)
                #pragma unroll
                for (int r = 0; r < 4; ++r) {
                    const int gr = row0 + wr * 64 + mi * 16 + kcl * 4 + r;
                    o[(size_t)gr * 256 + n] = acc[mi][ni][r] + bv;
                }
        }
    }
}

// ---------------------------------------------------------------------------
// Sampling: one wave per (b,h,q); half-wave = one (l,p) sample, d = lane&31.
// Logits split across halves (12 regs each, shfl-combined softmax).
// Bijective XCD swizzle: each XCD gets a contiguous 2048-block (4 slab) range.
// ---------------------------------------------------------------------------
__global__ __launch_bounds__(256, 8) void sample_kernel(
    const ushort* __restrict__ value,   // [B][NH][S][HD] bf16
    const float*  __restrict__ projQ,   // [8192][576] : [0:384)=off, [384:576)=logits
    const float*  __restrict__ refp,    // [B][NQ][2]
    ushort* __restrict__ out_preB)      // [8192][256] bf16
{
    const int wib  = threadIdx.x >> 6;
    const int lane = threadIdx.x & 63;
    const int half = lane >> 5, dl = lane & 31;

    const int bid = blockIdx.x;
    const int swz = (bid & 7) * 2048 + (bid >> 3);   // 16384 % 8 == 0: bijective
    const int bh = swz >> 9;
    const int q  = ((swz & 511) << 2) + wib;
    const int b  = bh >> 3, h = bh & 7;
    const int row = b * NQ + q;

    // split softmax: this half holds logits j = 2*jj + half
    const float* lg = projQ + (size_t)row * 576 + 384 + h * 24 + half;
    float l[12];
    float m = -1e30f;
    #pragma unroll
    for (int j = 0; j < 12; ++j) { l[j] = lg[2 * j]; m = fmaxf(m, l[j]); }
    m = fmaxf(m, __shfl_xor(m, 32));
    float s = 0.f;
    #pragma unroll
    for (int j = 0; j < 12; ++j) { l[j] = __expf(l[j] - m); s += l[j]; }
    s += __shfl_xor(s, 32);
    const float inv = 1.0f / s;

    const float refx = refp[(size_t)row * 2 + 0];
    const float refy = refp[(size_t)row * 2 + 1];
    const float* off = projQ + (size_t)row * 576 + h * 48 + half * 2;

    const uint vbh = (uint)(b * NH_ + h) * (uint)(S_ * HD_);
    float acc = 0.f;
    #pragma unroll
    for (int it = 0; it < 12; ++it) {
        const int lvl = it >> 2;                     // compile-time after unroll
        const int w = kLW[lvl], hh = kLH[lvl];
        const uint vbase = vbh + (uint)kLSTART[lvl] * HD_ + dl;

        const float ox = off[it * 4 + 0];
        const float oy = off[it * 4 + 1];
        const float x = fmaf(refx, (float)w,  ox) - 0.5f;
        const float y = fmaf(refy, (float)hh, oy) - 0.5f;
        const float x0f = floorf(x), y0f = floorf(y);
        const float fx = x - x0f, fy = y - y0f;
        const int ix = (int)x0f, iy = (int)y0f;

        const float cx0 = (ix >= 0 && ix < w)         ? (1.f - fx) : 0.f;
        const float cx1 = (ix + 1 >= 0 && ix + 1 < w) ? fx         : 0.f;
        const float cy0 = (iy >= 0 && iy < hh)         ? (1.f - fy) : 0.f;
        const float cy1 = (iy + 1 >= 0 && iy + 1 < hh) ? fy         : 0.f;
        const int xc0 = min(max(ix, 0), w - 1),  xc1 = min(max(ix + 1, 0), w - 1);
        const int yc0 = min(max(iy, 0), hh - 1), yc1 = min(max(iy + 1, 0), hh - 1);

        const uint r0 = vbase + (uint)(yc0 * w) * HD_;
        const uint r1 = vbase + (uint)(yc1 * w) * HD_;
        const float v00 = bf2f(value[r0 + (uint)xc0 * HD_]);
        const float v10 = bf2f(value[r0 + (uint)xc1 * HD_]);
        const float v01 = bf2f(value[r1 + (uint)xc0 * HD_]);
        const float v11 = bf2f(value[r1 + (uint)xc1 * HD_]);

        const float sv = cy0 * (cx0 * v00 + cx1 * v10) + cy1 * (cx0 * v01 + cx1 * v11);
        acc = fmaf(l[it] * inv, sv, acc);
    }

    acc += __shfl_xor(acc, 32);
    if (half == 0)
        out_preB[(size_t)row * 256 + h * HD_ + dl] = f2bf(acc);
}

extern "C" void kernel_launch(void* const* d_in, const int* in_sizes, int n_in,
                              void* d_out, int out_size, void* d_ws, size_t ws_size,
                              hipStream_t stream)
{
    const float* query  = (const float*)d_in[0];
    const float* memory = (const float*)d_in[1];
    const float* refp   = (const float*)d_in[2];
    const float* W_off  = (const float*)d_in[3];
    const float* b_off  = (const float*)d_in[4];
    const float* W_attn = (const float*)d_in[5];
    const float* b_attn = (const float*)d_in[6];
    const float* W_val  = (const float*)d_in[7];
    const float* b_val  = (const float*)d_in[8];
    const float* W_out  = (const float*)d_in[9];
    const float* b_out  = (const float*)d_in[10];

    // ws layout (ushort units). memB region is reused for projQ+out_preB
    // after gemm<0> consumes it (strictly ordered on one stream).
    ushort* ws       = (ushort*)d_ws;
    ushort* memB     = ws;                        // 13,440,000
    ushort* queryB   = memB + 13440000;           //  2,097,152
    ushort* W_valT   = queryB + 2097152;          //     65,536
    ushort* WcatT    = W_valT + 65536;            //    147,456
    ushort* W_outT   = WcatT + 147456;            //     65,536
    ushort* valueB   = W_outT + 65536;            // 13,440,000   (total 58.5 MB)
    float*  projQ    = (float*)memB;              //  4,718,592 f32 (aliases memB)
    ushort* out_preB = memB + 9437184;            //  2,097,152 (aliases memB tail)

    hipLaunchKernelGGL(convert_kernel, dim3(8675), dim3(256), 0, stream,
                       memory, query, W_off, W_attn, W_val, W_out,
                       memB, queryB, WcatT, W_valT, W_outT);
    hipLaunchKernelGGL((gemm_mfma<0>), dim3(103, 2, 4), dim3(256), 0, stream,
                       memB, W_valT, b_val, nullptr, (void*)valueB);
    hipLaunchKernelGGL((gemm_mfma<1>), dim3(64, 5, 1), dim3(256), 0, stream,
                       queryB, WcatT, b_off, b_attn, (void*)projQ);
    hipLaunchKernelGGL(sample_kernel, dim3(16384), dim3(256), 0, stream,
                       valueB, projQ, refp, out_preB);
    hipLaunchKernelGGL((gemm_mfma<2>), dim3(64, 2, 1), dim3(256), 0, stream,
                       out_preB, W_outT, b_out, nullptr, (void*)d_out);
}